// Round 7
// baseline (358.359 us; speedup 1.0000x reference)
//
#include <hip/hip_runtime.h>

// Problem constants: B=32, S=128, H=512, K=8
#define BB 32
#define SS 128
#define HH 512
#define KC 8
#define NN 4096  // KC*HH

typedef __attribute__((ext_vector_type(8))) short bf16x8;
typedef __attribute__((ext_vector_type(4))) float f32x4;

__device__ __forceinline__ unsigned short f2bf(float f) {
  unsigned int u = __float_as_uint(f);
  u += 0x7fffu + ((u >> 16) & 1u);   // round-to-nearest-even
  return (unsigned short)(u >> 16);
}
__device__ __forceinline__ float bf2f(unsigned short h) {
  return __uint_as_float(((unsigned int)h) << 16);
}
__device__ __forceinline__ float tanh_fast(float x) {
  float e = __expf(2.0f * x);
  return 1.0f - 2.0f / (e + 1.0f);
}
__device__ __forceinline__ void async16(const void* g, void* lds) {
  __builtin_amdgcn_global_load_lds(
      (const __attribute__((address_space(1))) unsigned int*)g,
      (__attribute__((address_space(3))) unsigned int*)lds, 16, 0, 0);
}

// ---- merged conversion kernel (verified) ----------------------------------
// blocks [0,4096): A/P fp32 [B,S,H] -> hi/lo row-major + hi-only [B,H,S].
// blocks [4096,8192): G [512,4096] fp32 -> G^T [4096,512] hi/lo bf16.
__global__ __launch_bounds__(256) void convert_all(
    const float* __restrict__ Xa, const float* __restrict__ Xb,
    unsigned short* __restrict__ hia, unsigned short* __restrict__ loa,
    unsigned short* __restrict__ hiTa,
    unsigned short* __restrict__ hib, unsigned short* __restrict__ lob,
    unsigned short* __restrict__ hiTb,
    const float* __restrict__ Ga, const float* __restrict__ Gb,
    unsigned short* __restrict__ gha, unsigned short* __restrict__ gla,
    unsigned short* __restrict__ ghb, unsigned short* __restrict__ glb) {
  __shared__ float t[32][33];
  const int idx = blockIdx.x;
  const int tx = threadIdx.x & 31, ty = threadIdx.x >> 5;
  if (idx < 4096) {
    const int z = idx >> 11, rem = idx & 2047;
    const int h0 = (rem & 15) * 32;
    const int y = rem >> 4;
    const int s0 = (y & 3) * 32;
    const size_t b = y >> 2;
    const float* X = z ? Xb : Xa;
    unsigned short* hi = z ? hib : hia;
    unsigned short* lo = z ? lob : loa;
    unsigned short* hiT = z ? hiTb : hiTa;
#pragma unroll
    for (int r = 0; r < 4; ++r) {
      float f = X[b * (SS * HH) + (size_t)(s0 + ty + r * 8) * HH + h0 + tx];
      t[ty + r * 8][tx] = f;
      size_t o = b * (SS * HH) + (size_t)(s0 + ty + r * 8) * HH + h0 + tx;
      unsigned short h = f2bf(f);
      hi[o] = h;
      lo[o] = f2bf(f - bf2f(h));
    }
    __syncthreads();
#pragma unroll
    for (int r = 0; r < 4; ++r) {
      float f = t[tx][ty + r * 8];
      size_t o = b * (SS * HH) + (size_t)(h0 + ty + r * 8) * SS + s0 + tx;
      hiT[o] = f2bf(f);
    }
  } else {
    const int j = idx - 4096;
    const int z = j >> 11, rem = j & 2047;
    const int bx = (rem & 127) * 32;  // n
    const int by = (rem >> 7) * 32;   // k
    const float* G = z ? Gb : Ga;
    unsigned short* hiT = z ? ghb : gha;
    unsigned short* loT = z ? glb : gla;
#pragma unroll
    for (int r = 0; r < 4; ++r)
      t[ty + r * 8][tx] = G[(size_t)(by + ty + r * 8) * NN + bx + tx];
    __syncthreads();
#pragma unroll
    for (int r = 0; r < 4; ++r) {
      float f = t[tx][ty + r * 8];
      size_t o = (size_t)(bx + ty + r * 8) * HH + by + tx;
      unsigned short h = f2bf(f);
      hiT[o] = h;
      loT[o] = f2bf(f - bf2f(h));
    }
  }
}

// ---- fused proj+score: block (k, b, br) -----------------------------------
// v7 = v2 schedule (round-1/6, 137us verified) with 8 WAVES per block
// (512 threads), same 128x128 tile / 2x32KB double buffer / barrier
// structure / XOR swizzle. Wave grid 2x4: each wave owns 64 rows x 32 cols
// (acc[4][2]). Raises occupancy 2 -> 4 waves/SIMD at VGPR<=128 (m69) for
// latency hiding; per-CU work unchanged.
// Staging: wave w covers 16 rows per region (srow = w*16 + (L>>2)); swizzle
// algebra unchanged (w*16 multiple of 8 -> (row>>1)&3 = (L>>3)&3).
// Buffer map (per 32KB half): Ah/proj-hi @0, Al/proj-lo @8K, Bh/Rh @16K,
// Bl/Rl @24K.
__global__ __launch_bounds__(512, 4) void fused_score(
    const unsigned short* __restrict__ Ahi, const unsigned short* __restrict__ Alo,
    const unsigned short* __restrict__ Phi, const unsigned short* __restrict__ Plo,
    const unsigned short* __restrict__ G1h, const unsigned short* __restrict__ G1l,
    const unsigned short* __restrict__ G2h, const unsigned short* __restrict__ G2l,
    const float* __restrict__ v1, const float* __restrict__ v2,
    float* __restrict__ scoreBuf, int bc) {
  __shared__ __align__(16) char smem[65536];
  const int k = blockIdx.x;   // fast dim: id mod 8 == k -> one k per XCD
  const int b = blockIdx.y;
  const int brx = blockIdx.z;
  const int tid = threadIdx.x, w = tid >> 6, L = tid & 63;
  const int wm = w >> 2, wn = w & 3;   // 2x4 wave grid: 64 rows x 32 cols each
  const int q = L >> 4, c = L & 15;

  // Left operand: aspect A for BOTH branches (faithful to source).
  const unsigned short* Ah = Ahi + (size_t)b * SS * HH;
  const unsigned short* Al = Alo + (size_t)b * SS * HH;
  const unsigned short* Gh = brx ? G2h : G1h;
  const unsigned short* Gl = brx ? G2l : G1l;
  // Right matrix: branch0 -> polarity, branch1 -> aspect.
  const unsigned short* Rh = (brx ? Ahi : Phi) + (size_t)b * SS * HH;
  const unsigned short* Rl = (brx ? Alo : Plo) + (size_t)b * SS * HH;

  // Staging: wave w covers rows w*16..w*16+15 (one async16 per region).
  // Source col slot pre-swizzled so linear LDS dest yields
  // LDS(row, sp) = global slot sp ^ ((row>>1)&3).
  const int srow = w * 16 + (L >> 2);
  const int slotS = ((L & 3) ^ ((L >> 3) & 3)) * 8;  // swizzled source col (shorts)
  const unsigned short* pAh = Ah + (size_t)srow * HH + slotS;
  const unsigned short* pAl = Al + (size_t)srow * HH + slotS;
  const unsigned short* pRh = Rh + (size_t)srow * HH + slotS;
  const unsigned short* pRl = Rl + (size_t)srow * HH + slotS;
  const unsigned lbase = (unsigned)w * 1024;

  // Reads: logical slot q at row r lives at phys slot q ^ ((r>>1)&3).
  const int xr = ((L & 15) >> 1) & 3;
  const int rslot = ((q ^ xr) << 4);                    // bytes
  const int arB = (wm * 64 + (L & 15)) * 64 + rslot;    // + i*1024 per i (4 frags)
  const int brB = (wn * 32 + (L & 15)) * 64 + rslot;    // + j*1024 per j (2 frags)

  f32x4 raw[4][2];
#pragma unroll
  for (int i = 0; i < 4; ++i)
#pragma unroll
    for (int j = 0; j < 2; ++j) raw[i][j] = (f32x4)(0.0f);

  auto stageA = [&](int gc, int kt, int buf) {
    const size_t n0 = (size_t)k * 512 + (size_t)gc * 128;
    const unsigned short* pBh = Gh + (n0 + srow) * HH + slotS;
    const unsigned short* pBl = Gl + (n0 + srow) * HH + slotS;
    const int k0 = kt * 32;
    char* bb = smem + buf * 32768;
    async16(pAh + k0, bb + lbase);
    async16(pAl + k0, bb + 8192 + lbase);
    async16(pBh + k0, bb + 16384 + lbase);
    async16(pBl + k0, bb + 24576 + lbase);
  };

  auto stageR = [&](int gc, int sl, int buf) {
    const int gg = gc * 128 + sl * 32;
    char* bb = smem + buf * 32768;
    async16(pRh + gg, bb + 16384 + lbase);
    async16(pRl + gg, bb + 24576 + lbase);
  };

  auto computeA = [&](f32x4 (&acc)[4][2], int buf) {
    const char* bb = smem + buf * 32768;
    bf16x8 ah[4], al[4], bh[2], bl[2];
#pragma unroll
    for (int i = 0; i < 4; ++i) {
      ah[i] = *(const bf16x8*)(bb + arB + i * 1024);
      al[i] = *(const bf16x8*)(bb + 8192 + arB + i * 1024);
    }
#pragma unroll
    for (int j = 0; j < 2; ++j) {
      bh[j] = *(const bf16x8*)(bb + 16384 + brB + j * 1024);
      bl[j] = *(const bf16x8*)(bb + 24576 + brB + j * 1024);
    }
    __builtin_amdgcn_s_setprio(1);
#pragma unroll
    for (int i = 0; i < 4; ++i)
#pragma unroll
      for (int j = 0; j < 2; ++j) {
        acc[i][j] = __builtin_amdgcn_mfma_f32_16x16x32_bf16(ah[i], bh[j], acc[i][j], 0, 0, 0);
        acc[i][j] = __builtin_amdgcn_mfma_f32_16x16x32_bf16(ah[i], bl[j], acc[i][j], 0, 0, 0);
        acc[i][j] = __builtin_amdgcn_mfma_f32_16x16x32_bf16(al[i], bh[j], acc[i][j], 0, 0, 0);
      }
    __builtin_amdgcn_s_setprio(0);
  };

  auto computeB = [&](int buf) {
    const char* bb = smem + buf * 32768;
    bf16x8 sah[4], sal[4], sbh[2], sbl[2];
#pragma unroll
    for (int i = 0; i < 4; ++i) {
      sah[i] = *(const bf16x8*)(bb + arB + i * 1024);
      sal[i] = *(const bf16x8*)(bb + 8192 + arB + i * 1024);
    }
#pragma unroll
    for (int j = 0; j < 2; ++j) {
      sbh[j] = *(const bf16x8*)(bb + 16384 + brB + j * 1024);
      sbl[j] = *(const bf16x8*)(bb + 24576 + brB + j * 1024);
    }
    __builtin_amdgcn_s_setprio(1);
#pragma unroll
    for (int i = 0; i < 4; ++i)
#pragma unroll
      for (int j = 0; j < 2; ++j) {
        raw[i][j] = __builtin_amdgcn_mfma_f32_16x16x32_bf16(sah[i], sbh[j], raw[i][j], 0, 0, 0);
        raw[i][j] = __builtin_amdgcn_mfma_f32_16x16x32_bf16(sah[i], sbl[j], raw[i][j], 0, 0, 0);
        raw[i][j] = __builtin_amdgcn_mfma_f32_16x16x32_bf16(sal[i], sbh[j], raw[i][j], 0, 0, 0);
      }
    __builtin_amdgcn_s_setprio(0);
  };

  // writeProj: slice sl (32 g-cols); owner waves wn == sl (both wm halves).
  // Owner's two j-frags cover exactly the slice; all acc indices static.
  auto writeProj = [&](const f32x4 (&acc)[4][2], int sl, int buf) {
    if (wn == sl) {
      unsigned short* ph = (unsigned short*)(smem + buf * 32768);
      unsigned short* pl = ph + 4096;
#pragma unroll
      for (int i = 0; i < 4; ++i)
#pragma unroll
        for (int j = 0; j < 2; ++j) {
          f32x4 vfr = acc[i][j];
#pragma unroll
          for (int r = 0; r < 4; ++r) {
            const int row = wm * 64 + i * 16 + q * 4 + r;
            const int gl = j * 16 + c;
            const int ad = row * 32 + ((((gl >> 3) ^ ((row >> 1) & 3)) << 3)) + (gl & 7);
            float f = vfr[r];
            unsigned short h = f2bf(f);
            ph[ad] = h;
            pl[ad] = f2bf(f - bf2f(h));
          }
        }
    }
  };

  // ---- pipelined main loop (v2 schedule, unchanged) ----
  stageA(0, 0, 0);
  __syncthreads();

  for (int gc = 0; gc < 4; ++gc) {
    f32x4 acc[4][2];
#pragma unroll
    for (int i = 0; i < 4; ++i)
#pragma unroll
      for (int j = 0; j < 2; ++j) acc[i][j] = (f32x4)(0.0f);

    // phase A: kt 0..14 prefetch next A-tile; kt 15 prefetches R slice 0 and
    // writes proj slice 0 (buf0 A-region is dead after kt=14's barrier).
    for (int kt = 0; kt < 15; ++kt) {
      stageA(gc, kt + 1, (kt + 1) & 1);
      computeA(acc, kt & 1);
      __syncthreads();
    }
    stageR(gc, 0, 0);
    computeA(acc, 1);
    writeProj(acc, 0, 0);
    __syncthreads();

    // phase B: slice sl reads buf sl&1; slice sl+1 (R stage + proj write) is
    // produced into buf^1 during sl's compute. At sl==3, prefetch next gc's
    // first A-tile into buf0 (last read at sl==2, barrier-separated).
#pragma unroll
    for (int sl = 0; sl < 4; ++sl) {
      if (sl < 3) stageR(gc, sl + 1, (sl + 1) & 1);
      else if (gc < 3) stageA(gc + 1, 0, 0);
      computeB(sl & 1);
      if (sl < 3) writeProj(acc, sl + 1, (sl + 1) & 1);
      __syncthreads();
    }
  }

  // ---------- epilogue: plain stores to this block's own k-slice ----------
  const float vk = (brx ? v2 : v1)[k];
  float* dst = scoreBuf + (((size_t)brx * bc + b) * KC + k) * (SS * SS);
#pragma unroll
  for (int i = 0; i < 4; ++i)
#pragma unroll
    for (int j = 0; j < 2; ++j) {
      const int row0 = wm * 64 + i * 16 + q * 4;
      const int col = wn * 32 + j * 16 + c;
#pragma unroll
      for (int r = 0; r < 4; ++r)
        dst[(size_t)(row0 + r) * SS + col] = vk * tanh_fast(raw[i][j][r]);
    }
}

// ---- k-sum + softmax over t -> attn weights bf16-hi -----------------------
// grid (groups = bc*2, 8 rt); block = 16 s-rows x 128 t.
__global__ __launch_bounds__(256) void softmax_attn(
    const float* __restrict__ scoreBuf, unsigned short* __restrict__ attnW) {
  const int x = blockIdx.x, rt = blockIdx.y;
  const int tid = threadIdx.x, tx = tid & 15, ty = tid >> 4;
  const size_t rowoff = (size_t)(rt * 16 + ty) * SS + tx * 8;
  const float* src = scoreBuf + (size_t)x * KC * (SS * SS) + rowoff;
  float sc[8];
#pragma unroll
  for (int j = 0; j < 8; ++j) sc[j] = 0.0f;
#pragma unroll
  for (int k = 0; k < KC; ++k) {
    float4 a0 = *(const float4*)&src[(size_t)k * (SS * SS)];
    float4 a1 = *(const float4*)&src[(size_t)k * (SS * SS) + 4];
    sc[0] += a0.x; sc[1] += a0.y; sc[2] += a0.z; sc[3] += a0.w;
    sc[4] += a1.x; sc[5] += a1.y; sc[6] += a1.z; sc[7] += a1.w;
  }
  float mx = sc[0];
#pragma unroll
  for (int j = 1; j < 8; ++j) mx = fmaxf(mx, sc[j]);
#pragma unroll
  for (int off = 1; off < 16; off <<= 1) mx = fmaxf(mx, __shfl_xor(mx, off, 16));
  float p[8], ssum = 0.0f;
#pragma unroll
  for (int j = 0; j < 8; ++j) { p[j] = __expf(sc[j] - mx); ssum += p[j]; }
#pragma unroll
  for (int off = 1; off < 16; off <<= 1) ssum += __shfl_xor(ssum, off, 16);
  float inv = 1.0f / ssum;
  ushort4 h0, h1;
  h0.x = f2bf(p[0] * inv); h0.y = f2bf(p[1] * inv);
  h0.z = f2bf(p[2] * inv); h0.w = f2bf(p[3] * inv);
  h1.x = f2bf(p[4] * inv); h1.y = f2bf(p[5] * inv);
  h1.z = f2bf(p[6] * inv); h1.w = f2bf(p[7] * inv);
  size_t abase = (size_t)x * (SS * SS) + rowoff;
  *(ushort4*)&attnW[abase] = h0;
  *(ushort4*)&attnW[abase + 4] = h1;
}

// ---- PV + residual: out[64 s x 128 h] = base + attn[64x128] @ V[128x128] --
__global__ __launch_bounds__(256) void pv_res2(
    const unsigned short* __restrict__ attnW,
    const unsigned short* __restrict__ PTh, const unsigned short* __restrict__ ATh,
    const float* __restrict__ Abase, const float* __restrict__ Pbase,
    float* __restrict__ out1, float* __restrict__ out2, int bc) {
  __shared__ char smem[12288];  // A [64][32] 4 KB | B [128][32] 8 KB
  unsigned short* sm = (unsigned short*)smem;
  const int x = blockIdx.x;
  const int brx = (x >= bc) ? 1 : 0;
  const int b = x - (brx ? bc : 0);
  const int hc = blockIdx.y & 3, sh = blockIdx.y >> 2;
  const int tid = threadIdx.x, w = tid >> 6, L = tid & 63;
  const int wm = w >> 1, wn = w & 1;

  const unsigned short* Aw = attnW + (size_t)x * (SS * SS) + (size_t)(sh * 64) * SS;
  const unsigned short* Vh = (brx ? ATh : PTh) + (size_t)b * HH * SS + (size_t)(hc * 128) * SS;
  const float* base = (brx ? Pbase : Abase) + (size_t)b * SS * HH;
  float* outp = (brx ? out2 : out1) + (size_t)b * SS * HH;

  f32x4 acc[2][4];
#pragma unroll
  for (int i = 0; i < 2; ++i)
#pragma unroll
    for (int j = 0; j < 4; ++j) acc[i][j] = (f32x4)(0.0f);

  const int arow = w * 16 + (L >> 2);
  const int brow = w * 32 + (L >> 2);
  const int scol = (L & 3) * 8;
  const int afr = (wm * 32 + (L & 15)) * 32 + (L >> 4) * 8;
  const int bfr = 2048 + (wn * 64 + (L & 15)) * 32 + (L >> 4) * 8;

  for (int kt = 0; kt < 4; ++kt) {
    const int k0 = kt * 32;
    async16(Aw + (size_t)arow * SS + k0 + scol, smem + w * 1024);
    async16(Vh + (size_t)brow * SS + k0 + scol, smem + 4096 + w * 2048);
    async16(Vh + (size_t)(brow + 16) * SS + k0 + scol, smem + 4096 + w * 2048 + 1024);
    __syncthreads();
    bf16x8 af[2], bf[4];
#pragma unroll
    for (int i = 0; i < 2; ++i) af[i] = *(const bf16x8*)&sm[afr + i * 512];
#pragma unroll
    for (int j = 0; j < 4; ++j) bf[j] = *(const bf16x8*)&sm[bfr + j * 512];
#pragma unroll
    for (int i = 0; i < 2; ++i)
#pragma unroll
      for (int j = 0; j < 4; ++j)
        acc[i][j] = __builtin_amdgcn_mfma_f32_16x16x32_bf16(af[i], bf[j], acc[i][j], 0, 0, 0);
    __syncthreads();
  }

  const int q = L >> 4, c = L & 15;
#pragma unroll
  for (int i = 0; i < 2; ++i)
#pragma unroll
    for (int j = 0; j < 4; ++j) {
      const int srow = sh * 64 + wm * 32 + i * 16 + q * 4;
      const int hcol = hc * 128 + wn * 64 + j * 16 + c;
#pragma unroll
      for (int r = 0; r < 4; ++r) {
        size_t o = (size_t)(srow + r) * HH + hcol;
        outp[o] = base[o] + acc[i][j][r];
      }
    }
}

extern "C" void kernel_launch(void* const* d_in, const int* in_sizes, int n_in,
                              void* d_out, int out_size, void* d_ws, size_t ws_size,
                              hipStream_t stream) {
  const float* A  = (const float*)d_in[0];
  const float* P  = (const float*)d_in[1];
  const float* G1 = (const float*)d_in[2];
  const float* G2 = (const float*)d_in[3];
  const float* v1 = (const float*)d_in[4];
  const float* v2 = (const float*)d_in[5];
  float* out1 = (float*)d_out;
  float* out2 = out1 + (size_t)BB * SS * HH;

  const size_t NA = (size_t)BB * SS * HH;  // 2M
  const size_t NG = (size_t)HH * KC * HH;  // 2M
  unsigned short* Ahi = (unsigned short*)d_ws;
  unsigned short* Alo = Ahi + NA;
  unsigned short* Phi = Alo + NA;
  unsigned short* Plo = Phi + NA;
  unsigned short* G1h = Plo + NA;
  unsigned short* G1l = G1h + NG;
  unsigned short* G2h = G1l + NG;
  unsigned short* G2l = G2h + NG;
  unsigned short* ATh = G2l + NG;
  unsigned short* PTh = ATh + NA;

  const size_t fixedBytes = (6 * NA + 4 * NG) * sizeof(unsigned short);  // 40 MB
  // per batch: scoreBuf 2*KC*16K fp32 (1 MB) + attnW 2*16K bf16 (64 KB)
  const size_t perB = 2 * (size_t)SS * SS * (KC * sizeof(float) + sizeof(unsigned short));
  size_t rem = ws_size > fixedBytes ? ws_size - fixedBytes : 0;
  int Bc = (int)(rem / perB);
  if (Bc < 1) Bc = 1;
  if (Bc > BB) Bc = BB;
  float* scoreBuf = (float*)((char*)d_ws + fixedBytes);
  unsigned short* attnW = (unsigned short*)(scoreBuf + 2 * (size_t)Bc * KC * SS * SS);

  convert_all<<<dim3(8192), 256, 0, stream>>>(
      A, P, Ahi, Alo, ATh, Phi, Plo, PTh, G1, G2, G1h, G1l, G2h, G2l);

  for (int b0 = 0; b0 < BB; b0 += Bc) {
    int bc = (Bc < BB - b0) ? Bc : (BB - b0);
    size_t off = (size_t)b0 * SS * HH;  // element offset (both layouts)
    fused_score<<<dim3(KC, bc, 2), 512, 0, stream>>>(
        Ahi + off, Alo + off, Phi + off, Plo + off,
        G1h, G1l, G2h, G2l, v1, v2, scoreBuf, bc);
    softmax_attn<<<dim3(bc * 2, 8), 256, 0, stream>>>(scoreBuf, attnW);
    pv_res2<<<dim3(bc * 2, 8), 256, 0, stream>>>(
        attnW, PTh + off, ATh + off, A + off, P + off,
        out1 + off, out2 + off, bc);
  }
}

// Round 8
// 221.923 us; speedup vs baseline: 1.6148x; 1.6148x over previous
//
#include <hip/hip_runtime.h>

// Problem constants: B=32, S=128, H=512, K=8
#define BB 32
#define SS 128
#define HH 512
#define KC 8
#define NN 4096  // KC*HH

typedef __attribute__((ext_vector_type(8))) short bf16x8;
typedef __attribute__((ext_vector_type(8))) _Float16 f16x8;
typedef __attribute__((ext_vector_type(4))) float f32x4;

__device__ __forceinline__ unsigned short f2bf(float f) {
  unsigned int u = __float_as_uint(f);
  u += 0x7fffu + ((u >> 16) & 1u);   // round-to-nearest-even
  return (unsigned short)(u >> 16);
}
__device__ __forceinline__ float bf2f(unsigned short h) {
  return __uint_as_float(((unsigned int)h) << 16);
}
__device__ __forceinline__ unsigned short f2fp16(float f) {
  union { _Float16 h; unsigned short u; } cv;
  cv.h = (_Float16)f;                // v_cvt_f16_f32, RTN
  return cv.u;
}
__device__ __forceinline__ float tanh_fast(float x) {
  float e = __expf(2.0f * x);
  return 1.0f - 2.0f / (e + 1.0f);
}
__device__ __forceinline__ void async16(const void* g, void* lds) {
  __builtin_amdgcn_global_load_lds(
      (const __attribute__((address_space(1))) unsigned int*)g,
      (__attribute__((address_space(3))) unsigned int*)lds, 16, 0, 0);
}

// ---- merged conversion kernel ---------------------------------------------
// blocks [0,4096): A/P fp32 [B,S,H] -> bf16 hi/lo row-major, fp16 [B,H,S]
//                  transposed (V), and (A only) fp16 row-major (phase-A left).
// blocks [4096,8192): G [512,4096] fp32 -> G^T [4096,512] fp16 (single).
__global__ __launch_bounds__(256) void convert_all(
    const float* __restrict__ Xa, const float* __restrict__ Xb,
    unsigned short* __restrict__ hia, unsigned short* __restrict__ loa,
    unsigned short* __restrict__ hiTa,
    unsigned short* __restrict__ hib, unsigned short* __restrict__ lob,
    unsigned short* __restrict__ hiTb,
    unsigned short* __restrict__ af16,
    const float* __restrict__ Ga, const float* __restrict__ Gb,
    unsigned short* __restrict__ g1f, unsigned short* __restrict__ g2f) {
  __shared__ float t[32][33];
  const int idx = blockIdx.x;
  const int tx = threadIdx.x & 31, ty = threadIdx.x >> 5;
  if (idx < 4096) {
    const int z = idx >> 11, rem = idx & 2047;
    const int h0 = (rem & 15) * 32;
    const int y = rem >> 4;
    const int s0 = (y & 3) * 32;
    const size_t b = y >> 2;
    const float* X = z ? Xb : Xa;
    unsigned short* hi = z ? hib : hia;
    unsigned short* lo = z ? lob : loa;
    unsigned short* hiT = z ? hiTb : hiTa;
#pragma unroll
    for (int r = 0; r < 4; ++r) {
      float f = X[b * (SS * HH) + (size_t)(s0 + ty + r * 8) * HH + h0 + tx];
      t[ty + r * 8][tx] = f;
      size_t o = b * (SS * HH) + (size_t)(s0 + ty + r * 8) * HH + h0 + tx;
      unsigned short h = f2bf(f);
      hi[o] = h;
      lo[o] = f2bf(f - bf2f(h));
      if (!z) af16[o] = f2fp16(f);   // aspect is the left operand of BOTH branches
    }
    __syncthreads();
#pragma unroll
    for (int r = 0; r < 4; ++r) {
      float f = t[tx][ty + r * 8];
      size_t o = b * (SS * HH) + (size_t)(h0 + ty + r * 8) * SS + s0 + tx;
      hiT[o] = f2fp16(f);            // V^T now fp16 (pv uses f16 MFMA)
    }
  } else {
    const int j = idx - 4096;
    const int z = j >> 11, rem = j & 2047;
    const int bx = (rem & 127) * 32;  // n
    const int by = (rem >> 7) * 32;   // k
    const float* G = z ? Gb : Ga;
    unsigned short* gf = z ? g2f : g1f;
#pragma unroll
    for (int r = 0; r < 4; ++r)
      t[ty + r * 8][tx] = G[(size_t)(by + ty + r * 8) * NN + bx + tx];
    __syncthreads();
#pragma unroll
    for (int r = 0; r < 4; ++r) {
      float f = t[tx][ty + r * 8];
      size_t o = (size_t)(bx + ty + r * 8) * HH + by + tx;
      gf[o] = f2fp16(f);             // fp16 single (phase A is G's only consumer)
    }
  }
}

// ---- fused proj+score: block (k, b, br) -----------------------------------
// v8 = v2 sync structure (proven 137us) with fp16 single-product phase A at
// BK=64 per step: 8 A-steps/gc (vs 16), 16 MFMA-pairs/step/wave.
//   Phase A buffer (32KB half): Af16 [128 s][64 h] @0 (16KB) | Gf16 [128 n][64 h] @16K.
//   8-slot XOR swizzle: LDS(row, s) holds global slot s ^ (row&7); staged via
//   pre-swizzled global source cols (linear global_load_lds dest).
// Phase B: byte-for-byte v2 (bf16 hi/lo 3-product; proj@0/8K, R@16K/24K,
//   (row>>1)&3 swizzle). Same barriers, same buffer rotation, same epilogue.
__global__ __launch_bounds__(256, 2) void fused_score(
    const unsigned short* __restrict__ Ahi, const unsigned short* __restrict__ Alo,
    const unsigned short* __restrict__ Phi, const unsigned short* __restrict__ Plo,
    const unsigned short* __restrict__ Af16,
    const unsigned short* __restrict__ G1f, const unsigned short* __restrict__ G2f,
    const float* __restrict__ v1, const float* __restrict__ v2,
    float* __restrict__ scoreBuf, int bc) {
  __shared__ __align__(16) char smem[65536];
  const int k = blockIdx.x;   // fast dim: id mod 8 == k -> one k per XCD
  const int b = blockIdx.y;
  const int brx = blockIdx.z;
  const int tid = threadIdx.x, w = tid >> 6, L = tid & 63;
  const int wm = w >> 1, wn = w & 1;
  const int q = L >> 4, c = L & 15;

  // fp16 operands for phase A (left = aspect A for BOTH branches).
  const unsigned short* Af = Af16 + (size_t)b * SS * HH;
  const unsigned short* Gf = brx ? G2f : G1f;
  // Right matrix (phase B): branch0 -> polarity, branch1 -> aspect (bf16 hi/lo).
  const unsigned short* Rh = (brx ? Ahi : Phi) + (size_t)b * SS * HH;
  const unsigned short* Rl = (brx ? Alo : Plo) + (size_t)b * SS * HH;

  // ---- phase-A staging (fp16, 128 rows x 64 cols per region) ----
  // Thread covers row w*32 + c8*8 + (L>>3), slot L&7 (16B units, 8 slots/row).
  // Source col pre-swizzled: LDS(row, s) = global slot s ^ (row&7).
  const int rrA = L >> 3;
  const int scA = ((L & 7) ^ rrA) * 8;   // swizzled source col (elems)
  const unsigned short* pAf = Af + (size_t)(w * 32 + rrA) * HH + scA;
  const unsigned short* pGf = Gf + (size_t)(w * 32 + rrA) * HH + scA;

  // ---- phase-B staging (v2 exact): bf16, 4-slot (row>>1)&3 swizzle ----
  const int srow = w * 32 + (L >> 2);
  const int slotS = ((L & 3) ^ ((L >> 3) & 3)) * 8;
  const unsigned short* pRh = Rh + (size_t)srow * HH + slotS;
  const unsigned short* pRl = Rl + (size_t)srow * HH + slotS;
  const unsigned lbase = (unsigned)w * 2048;

  // phase-B reads (v2 exact): logical slot q at row r -> phys q ^ ((r>>1)&3).
  const int xr = ((L & 15) >> 1) & 3;
  const int rslot = ((q ^ xr) << 4);                    // bytes
  const int arB = (wm * 64 + (L & 15)) * 64 + rslot;    // + i*1024 per i
  const int brB = (wn * 64 + (L & 15)) * 64 + rslot;    // + j*1024 per j

  f32x4 raw[4][4];
#pragma unroll
  for (int i = 0; i < 4; ++i)
#pragma unroll
    for (int j = 0; j < 4; ++j) raw[i][j] = (f32x4)(0.0f);

  // stage phase-A step ks (K=64 cols of H) into buffer: 8 async16/wave.
  auto stageA = [&](int gc, int ks, int buf) {
    const int k0 = ks * 64;
    const size_t n0 = (size_t)k * 512 + (size_t)gc * 128;
    char* bb = smem + buf * 32768;
#pragma unroll
    for (int c8 = 0; c8 < 4; ++c8) {
      async16(pAf + (size_t)(c8 * 8) * HH + k0, bb + w * 4096 + c8 * 1024);
      async16(pGf + (n0 + c8 * 8) * HH + k0, bb + 16384 + w * 4096 + c8 * 1024);
    }
  };

  // stage R slice sl of gc (v2 exact): 4 async16/wave into @16K/@24K.
  auto stageR = [&](int gc, int sl, int buf) {
    const int gg = gc * 128 + sl * 32;
    char* bb = smem + buf * 32768;
    async16(pRh + gg, bb + 16384 + lbase);
    async16(pRh + gg + 16 * HH, bb + 16384 + lbase + 1024);
    async16(pRl + gg, bb + 24576 + lbase);
    async16(pRl + gg + 16 * HH, bb + 24576 + lbase + 1024);
  };

  // phase-A compute: fp16 single product, K=64 (two K=32 MFMA per acc cell).
  auto computeA = [&](f32x4 (&acc)[4][4], int buf) {
    const char* bb = smem + buf * 32768;
    f16x8 ah[4][2], bh[4][2];
#pragma unroll
    for (int i = 0; i < 4; ++i) {
      const int R = wm * 64 + i * 16 + (L & 15);
#pragma unroll
      for (int kk = 0; kk < 2; ++kk) {
        const int sl8 = (kk * 4 + q) ^ (L & 7);
        ah[i][kk] = *(const f16x8*)(bb + R * 128 + sl8 * 16);
      }
    }
#pragma unroll
    for (int j = 0; j < 4; ++j) {
      const int Rb = wn * 64 + j * 16 + (L & 15);
#pragma unroll
      for (int kk = 0; kk < 2; ++kk) {
        const int sl8 = (kk * 4 + q) ^ (L & 7);
        bh[j][kk] = *(const f16x8*)(bb + 16384 + Rb * 128 + sl8 * 16);
      }
    }
    __builtin_amdgcn_s_setprio(1);
#pragma unroll
    for (int i = 0; i < 4; ++i)
#pragma unroll
      for (int j = 0; j < 4; ++j) {
        acc[i][j] = __builtin_amdgcn_mfma_f32_16x16x32_f16(ah[i][0], bh[j][0], acc[i][j], 0, 0, 0);
        acc[i][j] = __builtin_amdgcn_mfma_f32_16x16x32_f16(ah[i][1], bh[j][1], acc[i][j], 0, 0, 0);
      }
    __builtin_amdgcn_s_setprio(0);
  };

  // phase-B compute (v2 exact): bf16 3-product into raw.
  auto computeB = [&](int buf) {
    const char* bb = smem + buf * 32768;
    bf16x8 sah[4], sal[4], sbh[4], sbl[4];
#pragma unroll
    for (int i = 0; i < 4; ++i) {
      sah[i] = *(const bf16x8*)(bb + arB + i * 1024);
      sal[i] = *(const bf16x8*)(bb + 8192 + arB + i * 1024);
    }
#pragma unroll
    for (int j = 0; j < 4; ++j) {
      sbh[j] = *(const bf16x8*)(bb + 16384 + brB + j * 1024);
      sbl[j] = *(const bf16x8*)(bb + 24576 + brB + j * 1024);
    }
    __builtin_amdgcn_s_setprio(1);
#pragma unroll
    for (int i = 0; i < 4; ++i)
#pragma unroll
      for (int j = 0; j < 4; ++j) {
        raw[i][j] = __builtin_amdgcn_mfma_f32_16x16x32_bf16(sah[i], sbh[j], raw[i][j], 0, 0, 0);
        raw[i][j] = __builtin_amdgcn_mfma_f32_16x16x32_bf16(sah[i], sbl[j], raw[i][j], 0, 0, 0);
        raw[i][j] = __builtin_amdgcn_mfma_f32_16x16x32_bf16(sal[i], sbh[j], raw[i][j], 0, 0, 0);
      }
    __builtin_amdgcn_s_setprio(0);
  };

  // writeProj (v2 exact): slice sl, owner waves wn == sl>>1; swizzled ds_write.
  auto writeProj = [&](const f32x4 (&acc)[4][4], int sl, int buf) {
    if (wn == (sl >> 1)) {
      const int jj0 = (sl & 1) * 2;
      unsigned short* ph = (unsigned short*)(smem + buf * 32768);
      unsigned short* pl = ph + 4096;
#pragma unroll
      for (int i = 0; i < 4; ++i)
#pragma unroll
        for (int jd = 0; jd < 2; ++jd) {
          f32x4 vfr = acc[i][jj0 + jd];
#pragma unroll
          for (int r = 0; r < 4; ++r) {
            const int row = wm * 64 + i * 16 + q * 4 + r;
            const int gl = jd * 16 + c;
            const int ad = row * 32 + ((((gl >> 3) ^ ((row >> 1) & 3)) << 3)) + (gl & 7);
            float f = vfr[r];
            unsigned short h = f2bf(f);
            ph[ad] = h;
            pl[ad] = f2bf(f - bf2f(h));
          }
        }
    }
  };

  // ---- pipelined main loop (v2 schedule, 8 A-steps/gc) ----
  stageA(0, 0, 0);
  __syncthreads();

  for (int gc = 0; gc < 4; ++gc) {
    f32x4 acc[4][4];
#pragma unroll
    for (int i = 0; i < 4; ++i)
#pragma unroll
      for (int j = 0; j < 4; ++j) acc[i][j] = (f32x4)(0.0f);

    // A-steps ks=0..6 prefetch next A-step; ks=7 prefetches R slice 0 and
    // writes proj slice 0 into buf0 (buf0 A/G regions dead after ks=6 barrier).
    for (int ks = 0; ks < 7; ++ks) {
      stageA(gc, ks + 1, (ks + 1) & 1);
      computeA(acc, ks & 1);
      __syncthreads();
    }
    stageR(gc, 0, 0);
    computeA(acc, 1);
    writeProj(acc, 0, 0);
    __syncthreads();

    // phase B (v2 exact): slice sl reads buf sl&1; slice sl+1 produced into
    // buf^1 during sl's compute. At sl==3, prefetch next gc's first A-step
    // into buf0 (last read at sl==2, barrier-separated).
#pragma unroll
    for (int sl = 0; sl < 4; ++sl) {
      if (sl < 3) stageR(gc, sl + 1, (sl + 1) & 1);
      else if (gc < 3) stageA(gc + 1, 0, 0);
      computeB(sl & 1);
      if (sl < 3) writeProj(acc, sl + 1, (sl + 1) & 1);
      __syncthreads();
    }
  }

  // ---------- epilogue: plain stores to this block's own k-slice ----------
  const float vk = (brx ? v2 : v1)[k];
  float* dst = scoreBuf + (((size_t)brx * bc + b) * KC + k) * (SS * SS);
#pragma unroll
  for (int i = 0; i < 4; ++i)
#pragma unroll
    for (int j = 0; j < 4; ++j) {
      const int row0 = wm * 64 + i * 16 + q * 4;
      const int col = wn * 64 + j * 16 + c;
#pragma unroll
      for (int r = 0; r < 4; ++r)
        dst[(size_t)(row0 + r) * SS + col] = vk * tanh_fast(raw[i][j][r]);
    }
}

// ---- k-sum + softmax over t -> attn weights fp16 --------------------------
// grid (groups = bc*2, 8 rt); block = 16 s-rows x 128 t.
__global__ __launch_bounds__(256) void softmax_attn(
    const float* __restrict__ scoreBuf, unsigned short* __restrict__ attnW) {
  const int x = blockIdx.x, rt = blockIdx.y;
  const int tid = threadIdx.x, tx = tid & 15, ty = tid >> 4;
  const size_t rowoff = (size_t)(rt * 16 + ty) * SS + tx * 8;
  const float* src = scoreBuf + (size_t)x * KC * (SS * SS) + rowoff;
  float sc[8];
#pragma unroll
  for (int j = 0; j < 8; ++j) sc[j] = 0.0f;
#pragma unroll
  for (int k = 0; k < KC; ++k) {
    float4 a0 = *(const float4*)&src[(size_t)k * (SS * SS)];
    float4 a1 = *(const float4*)&src[(size_t)k * (SS * SS) + 4];
    sc[0] += a0.x; sc[1] += a0.y; sc[2] += a0.z; sc[3] += a0.w;
    sc[4] += a1.x; sc[5] += a1.y; sc[6] += a1.z; sc[7] += a1.w;
  }
  float mx = sc[0];
#pragma unroll
  for (int j = 1; j < 8; ++j) mx = fmaxf(mx, sc[j]);
#pragma unroll
  for (int off = 1; off < 16; off <<= 1) mx = fmaxf(mx, __shfl_xor(mx, off, 16));
  float p[8], ssum = 0.0f;
#pragma unroll
  for (int j = 0; j < 8; ++j) { p[j] = __expf(sc[j] - mx); ssum += p[j]; }
#pragma unroll
  for (int off = 1; off < 16; off <<= 1) ssum += __shfl_xor(ssum, off, 16);
  float inv = 1.0f / ssum;
  ushort4 h0, h1;
  h0.x = f2fp16(p[0] * inv); h0.y = f2fp16(p[1] * inv);
  h0.z = f2fp16(p[2] * inv); h0.w = f2fp16(p[3] * inv);
  h1.x = f2fp16(p[4] * inv); h1.y = f2fp16(p[5] * inv);
  h1.z = f2fp16(p[6] * inv); h1.w = f2fp16(p[7] * inv);
  size_t abase = (size_t)x * (SS * SS) + rowoff;
  *(ushort4*)&attnW[abase] = h0;
  *(ushort4*)&attnW[abase + 4] = h1;
}

// ---- PV + residual (fp16 MFMA): out = base + attn[64x128] @ V[128x128] ----
__global__ __launch_bounds__(256) void pv_res2(
    const unsigned short* __restrict__ attnW,
    const unsigned short* __restrict__ PTf, const unsigned short* __restrict__ ATf,
    const float* __restrict__ Abase, const float* __restrict__ Pbase,
    float* __restrict__ out1, float* __restrict__ out2, int bc) {
  __shared__ char smem[12288];  // A [64][32] 4 KB | B [128][32] 8 KB
  unsigned short* sm = (unsigned short*)smem;
  const int x = blockIdx.x;
  const int brx = (x >= bc) ? 1 : 0;
  const int b = x - (brx ? bc : 0);
  const int hc = blockIdx.y & 3, sh = blockIdx.y >> 2;
  const int tid = threadIdx.x, w = tid >> 6, L = tid & 63;
  const int wm = w >> 1, wn = w & 1;

  const unsigned short* Aw = attnW + (size_t)x * (SS * SS) + (size_t)(sh * 64) * SS;
  const unsigned short* Vh = (brx ? ATf : PTf) + (size_t)b * HH * SS + (size_t)(hc * 128) * SS;
  const float* base = (brx ? Pbase : Abase) + (size_t)b * SS * HH;
  float* outp = (brx ? out2 : out1) + (size_t)b * SS * HH;

  f32x4 acc[2][4];
#pragma unroll
  for (int i = 0; i < 2; ++i)
#pragma unroll
    for (int j = 0; j < 4; ++j) acc[i][j] = (f32x4)(0.0f);

  const int arow = w * 16 + (L >> 2);
  const int brow = w * 32 + (L >> 2);
  const int scol = (L & 3) * 8;
  const int afr = (wm * 32 + (L & 15)) * 32 + (L >> 4) * 8;
  const int bfr = 2048 + (wn * 64 + (L & 15)) * 32 + (L >> 4) * 8;

  for (int kt = 0; kt < 4; ++kt) {
    const int k0 = kt * 32;
    async16(Aw + (size_t)arow * SS + k0 + scol, smem + w * 1024);
    async16(Vh + (size_t)brow * SS + k0 + scol, smem + 4096 + w * 2048);
    async16(Vh + (size_t)(brow + 16) * SS + k0 + scol, smem + 4096 + w * 2048 + 1024);
    __syncthreads();
    f16x8 af[2], bf[4];
#pragma unroll
    for (int i = 0; i < 2; ++i) af[i] = *(const f16x8*)&sm[afr + i * 512];
#pragma unroll
    for (int j = 0; j < 4; ++j) bf[j] = *(const f16x8*)&sm[bfr + j * 512];
#pragma unroll
    for (int i = 0; i < 2; ++i)
#pragma unroll
      for (int j = 0; j < 4; ++j)
        acc[i][j] = __builtin_amdgcn_mfma_f32_16x16x32_f16(af[i], bf[j], acc[i][j], 0, 0, 0);
    __syncthreads();
  }

  const int q = L >> 4, c = L & 15;
#pragma unroll
  for (int i = 0; i < 2; ++i)
#pragma unroll
    for (int j = 0; j < 4; ++j) {
      const int srow = sh * 64 + wm * 32 + i * 16 + q * 4;
      const int hcol = hc * 128 + wn * 64 + j * 16 + c;
#pragma unroll
      for (int r = 0; r < 4; ++r) {
        size_t o = (size_t)(srow + r) * HH + hcol;
        outp[o] = base[o] + acc[i][j][r];
      }
    }
}

extern "C" void kernel_launch(void* const* d_in, const int* in_sizes, int n_in,
                              void* d_out, int out_size, void* d_ws, size_t ws_size,
                              hipStream_t stream) {
  const float* A  = (const float*)d_in[0];
  const float* P  = (const float*)d_in[1];
  const float* G1 = (const float*)d_in[2];
  const float* G2 = (const float*)d_in[3];
  const float* v1 = (const float*)d_in[4];
  const float* v2 = (const float*)d_in[5];
  float* out1 = (float*)d_out;
  float* out2 = out1 + (size_t)BB * SS * HH;

  const size_t NA = (size_t)BB * SS * HH;  // 2M
  const size_t NG = (size_t)HH * KC * HH;  // 2M
  unsigned short* Ahi = (unsigned short*)d_ws;
  unsigned short* Alo = Ahi + NA;
  unsigned short* Phi = Alo + NA;
  unsigned short* Plo = Phi + NA;
  unsigned short* Af16 = Plo + NA;
  unsigned short* G1f = Af16 + NA;
  unsigned short* G2f = G1f + NG;
  unsigned short* ATf = G2f + NG;
  unsigned short* PTf = ATf + NA;

  const size_t fixedBytes = (7 * NA + 2 * NG) * sizeof(unsigned short);  // 36 MB
  // per batch: scoreBuf 2*KC*16K fp32 (1 MB) + attnW 2*16K fp16 (64 KB)
  const size_t perB = 2 * (size_t)SS * SS * (KC * sizeof(float) + sizeof(unsigned short));
  size_t rem = ws_size > fixedBytes ? ws_size - fixedBytes : 0;
  int Bc = (int)(rem / perB);
  if (Bc < 1) Bc = 1;
  if (Bc > BB) Bc = BB;
  float* scoreBuf = (float*)((char*)d_ws + fixedBytes);
  unsigned short* attnW = (unsigned short*)(scoreBuf + 2 * (size_t)Bc * KC * SS * SS);

  convert_all<<<dim3(8192), 256, 0, stream>>>(
      A, P, Ahi, Alo, ATf, Phi, Plo, PTf, Af16, G1, G2, G1f, G2f);

  for (int b0 = 0; b0 < BB; b0 += Bc) {
    int bc = (Bc < BB - b0) ? Bc : (BB - b0);
    size_t off = (size_t)b0 * SS * HH;  // element offset (both layouts)
    fused_score<<<dim3(KC, bc, 2), 256, 0, stream>>>(
        Ahi + off, Alo + off, Phi + off, Plo + off, Af16 + off,
        G1f, G2f, v1, v2, scoreBuf, bc);
    softmax_attn<<<dim3(bc * 2, 8), 256, 0, stream>>>(scoreBuf, attnW);
    pv_res2<<<dim3(bc * 2, 8), 256, 0, stream>>>(
        attnW, PTf + off, ATf + off, A + off, P + off,
        out1 + off, out2 + off, bc);
  }
}

// Round 9
// 182.239 us; speedup vs baseline: 1.9664x; 1.2178x over previous
//
#include <hip/hip_runtime.h>

// Problem constants: B=32, S=128, H=512, K=8
#define BB 32
#define SS 128
#define HH 512
#define KC 8
#define NN 4096  // KC*HH

typedef __attribute__((ext_vector_type(8))) _Float16 f16x8;
typedef __attribute__((ext_vector_type(4))) float f32x4;

__device__ __forceinline__ unsigned short f2fp16(float f) {
  union { _Float16 h; unsigned short u; } cv;
  cv.h = (_Float16)f;                // v_cvt_f16_f32, RTN
  return cv.u;
}
__device__ __forceinline__ float tanh_fast(float x) {
  float e = __expf(2.0f * x);
  return 1.0f - 2.0f / (e + 1.0f);
}
__device__ __forceinline__ void async16(const void* g, void* lds) {
  __builtin_amdgcn_global_load_lds(
      (const __attribute__((address_space(1))) unsigned int*)g,
      (__attribute__((address_space(3))) unsigned int*)lds, 16, 0, 0);
}

// ---- merged conversion kernel ---------------------------------------------
// blocks [0,4096): A/P fp32 [B,S,H] -> fp16 row-major + fp16 [B,H,S] transposed.
// blocks [4096,8192): G [512,4096] fp32 -> G^T [4096,512] fp16.
__global__ __launch_bounds__(256) void convert_all(
    const float* __restrict__ Xa, const float* __restrict__ Xb,
    unsigned short* __restrict__ af16, unsigned short* __restrict__ pf16,
    unsigned short* __restrict__ aT16, unsigned short* __restrict__ pT16,
    const float* __restrict__ Ga, const float* __restrict__ Gb,
    unsigned short* __restrict__ g1f, unsigned short* __restrict__ g2f) {
  __shared__ float t[32][33];
  const int idx = blockIdx.x;
  const int tx = threadIdx.x & 31, ty = threadIdx.x >> 5;
  if (idx < 4096) {
    const int z = idx >> 11, rem = idx & 2047;
    const int h0 = (rem & 15) * 32;
    const int y = rem >> 4;
    const int s0 = (y & 3) * 32;
    const size_t b = y >> 2;
    const float* X = z ? Xb : Xa;
    unsigned short* xf = z ? pf16 : af16;
    unsigned short* xT = z ? pT16 : aT16;
#pragma unroll
    for (int r = 0; r < 4; ++r) {
      float f = X[b * (SS * HH) + (size_t)(s0 + ty + r * 8) * HH + h0 + tx];
      t[ty + r * 8][tx] = f;
      size_t o = b * (SS * HH) + (size_t)(s0 + ty + r * 8) * HH + h0 + tx;
      xf[o] = f2fp16(f);
    }
    __syncthreads();
#pragma unroll
    for (int r = 0; r < 4; ++r) {
      float f = t[tx][ty + r * 8];
      size_t o = b * (SS * HH) + (size_t)(h0 + ty + r * 8) * SS + s0 + tx;
      xT[o] = f2fp16(f);
    }
  } else {
    const int j = idx - 4096;
    const int z = j >> 11, rem = j & 2047;
    const int bx = (rem & 127) * 32;  // n
    const int by = (rem >> 7) * 32;   // k
    const float* G = z ? Gb : Ga;
    unsigned short* gf = z ? g2f : g1f;
#pragma unroll
    for (int r = 0; r < 4; ++r)
      t[ty + r * 8][tx] = G[(size_t)(by + ty + r * 8) * NN + bx + tx];
    __syncthreads();
#pragma unroll
    for (int r = 0; r < 4; ++r) {
      float f = t[tx][ty + r * 8];
      size_t o = (size_t)(bx + ty + r * 8) * HH + by + tx;
      gf[o] = f2fp16(f);
    }
  }
}

// ---- fused proj+score: block (k, b, br) -----------------------------------
// v9 = v8 sync structure (proven; r8 passed at 114us) with fp16 SINGLE
// product in phase B too (proj fp16, R fp16: 16 MFMA/slice vs 48) and fp16
// scoreBuf. Justification: r8 showed phase-A fp16 (raw err ~5e-3) moved
// absmax by exactly 0; phase-B fp16 adds error of the same magnitude.
//   Phase A buffer (32KB half): Af16 [128 s][64 h] @0 16KB | Gf16 @16K 16KB,
//     8-slot XOR swizzle (slot ^= row&7), staged via pre-swizzled source.
//   Phase B buffer: proj fp16 [128 s][32 g] @0 8KB | R fp16 [128 t][32 g]
//     @16K 8KB, 4-slot XOR swizzle (slot ^= (row>>1)&3) — v2's layout.
// Barrier schedule / buffer rotation / hazard structure: byte-for-byte v8.
__global__ __launch_bounds__(256, 2) void fused_score(
    const unsigned short* __restrict__ Af16, const unsigned short* __restrict__ Pf16,
    const unsigned short* __restrict__ G1f, const unsigned short* __restrict__ G2f,
    const float* __restrict__ v1, const float* __restrict__ v2,
    unsigned short* __restrict__ scoreH, int bc) {
  __shared__ __align__(16) char smem[65536];
  const int k = blockIdx.x;   // fast dim: id mod 8 == k -> one k per XCD
  const int b = blockIdx.y;
  const int brx = blockIdx.z;
  const int tid = threadIdx.x, w = tid >> 6, L = tid & 63;
  const int wm = w >> 1, wn = w & 1;
  const int q = L >> 4, c = L & 15;

  // Phase-A left = aspect for BOTH branches (faithful to source).
  const unsigned short* Af = Af16 + (size_t)b * SS * HH;
  const unsigned short* Gf = brx ? G2f : G1f;
  // Phase-B right: branch0 -> polarity, branch1 -> aspect.
  const unsigned short* Rf = (brx ? Af16 : Pf16) + (size_t)b * SS * HH;

  // ---- phase-A staging (fp16, 128 rows x 64 cols per region) ----
  const int rrA = L >> 3;
  const int scA = ((L & 7) ^ rrA) * 8;   // swizzled source col (elems)
  const unsigned short* pAf = Af + (size_t)(w * 32 + rrA) * HH + scA;
  const unsigned short* pGf = Gf + (size_t)(w * 32 + rrA) * HH + scA;

  // ---- phase-B staging: fp16 [128][32], 4-slot (row>>1)&3 swizzle ----
  const int srow = w * 32 + (L >> 2);
  const int slotS = ((L & 3) ^ ((L >> 3) & 3)) * 8;
  const unsigned short* pRf = Rf + (size_t)srow * HH + slotS;
  const unsigned lbase = (unsigned)w * 2048;

  // phase-B reads: logical slot q at row r -> phys q ^ ((r>>1)&3).
  const int xr = ((L & 15) >> 1) & 3;
  const int rslot = ((q ^ xr) << 4);                    // bytes
  const int arB = (wm * 64 + (L & 15)) * 64 + rslot;    // + i*1024 per i
  const int brB = (wn * 64 + (L & 15)) * 64 + rslot;    // + j*1024 per j

  f32x4 raw[4][4];
#pragma unroll
  for (int i = 0; i < 4; ++i)
#pragma unroll
    for (int j = 0; j < 4; ++j) raw[i][j] = (f32x4)(0.0f);

  // stage phase-A step ks (K=64 cols of H): 8 async16/wave.
  auto stageA = [&](int gc, int ks, int buf) {
    const int k0 = ks * 64;
    const size_t n0 = (size_t)k * 512 + (size_t)gc * 128;
    char* bb = smem + buf * 32768;
#pragma unroll
    for (int c8 = 0; c8 < 4; ++c8) {
      async16(pAf + (size_t)(c8 * 8) * HH + k0, bb + w * 4096 + c8 * 1024);
      async16(pGf + (n0 + c8 * 8) * HH + k0, bb + 16384 + w * 4096 + c8 * 1024);
    }
  };

  // stage R slice sl of gc: 2 async16/wave into @16K.
  auto stageR = [&](int gc, int sl, int buf) {
    const int gg = gc * 128 + sl * 32;
    char* bb = smem + buf * 32768;
    async16(pRf + gg, bb + 16384 + lbase);
    async16(pRf + gg + 16 * HH, bb + 16384 + lbase + 1024);
  };

  // phase-A compute: fp16 single product, K=64 (two K=32 MFMA per acc cell).
  auto computeA = [&](f32x4 (&acc)[4][4], int buf) {
    const char* bb = smem + buf * 32768;
    f16x8 ah[4][2], bh[4][2];
#pragma unroll
    for (int i = 0; i < 4; ++i) {
      const int R = wm * 64 + i * 16 + (L & 15);
#pragma unroll
      for (int kk = 0; kk < 2; ++kk) {
        const int sl8 = (kk * 4 + q) ^ (L & 7);
        ah[i][kk] = *(const f16x8*)(bb + R * 128 + sl8 * 16);
      }
    }
#pragma unroll
    for (int j = 0; j < 4; ++j) {
      const int Rb = wn * 64 + j * 16 + (L & 15);
#pragma unroll
      for (int kk = 0; kk < 2; ++kk) {
        const int sl8 = (kk * 4 + q) ^ (L & 7);
        bh[j][kk] = *(const f16x8*)(bb + 16384 + Rb * 128 + sl8 * 16);
      }
    }
    __builtin_amdgcn_s_setprio(1);
#pragma unroll
    for (int i = 0; i < 4; ++i)
#pragma unroll
      for (int j = 0; j < 4; ++j) {
        acc[i][j] = __builtin_amdgcn_mfma_f32_16x16x32_f16(ah[i][0], bh[j][0], acc[i][j], 0, 0, 0);
        acc[i][j] = __builtin_amdgcn_mfma_f32_16x16x32_f16(ah[i][1], bh[j][1], acc[i][j], 0, 0, 0);
      }
    __builtin_amdgcn_s_setprio(0);
  };

  // phase-B compute: fp16 single product, one K=32 MFMA per cell.
  auto computeB = [&](int buf) {
    const char* bb = smem + buf * 32768;
    f16x8 sa[4], sb[4];
#pragma unroll
    for (int i = 0; i < 4; ++i)
      sa[i] = *(const f16x8*)(bb + arB + i * 1024);
#pragma unroll
    for (int j = 0; j < 4; ++j)
      sb[j] = *(const f16x8*)(bb + 16384 + brB + j * 1024);
    __builtin_amdgcn_s_setprio(1);
#pragma unroll
    for (int i = 0; i < 4; ++i)
#pragma unroll
      for (int j = 0; j < 4; ++j)
        raw[i][j] = __builtin_amdgcn_mfma_f32_16x16x32_f16(sa[i], sb[j], raw[i][j], 0, 0, 0);
    __builtin_amdgcn_s_setprio(0);
  };

  // writeProj: slice sl, owner waves wn == sl>>1; swizzled fp16 ds_write.
  auto writeProj = [&](const f32x4 (&acc)[4][4], int sl, int buf) {
    if (wn == (sl >> 1)) {
      const int jj0 = (sl & 1) * 2;
      unsigned short* ph = (unsigned short*)(smem + buf * 32768);
#pragma unroll
      for (int i = 0; i < 4; ++i)
#pragma unroll
        for (int jd = 0; jd < 2; ++jd) {
          f32x4 vfr = acc[i][jj0 + jd];
#pragma unroll
          for (int r = 0; r < 4; ++r) {
            const int row = wm * 64 + i * 16 + q * 4 + r;
            const int gl = jd * 16 + c;
            const int ad = row * 32 + ((((gl >> 3) ^ ((row >> 1) & 3)) << 3)) + (gl & 7);
            ph[ad] = f2fp16(vfr[r]);
          }
        }
    }
  };

  // ---- pipelined main loop (v8 schedule, 8 A-steps/gc) ----
  stageA(0, 0, 0);
  __syncthreads();

  for (int gc = 0; gc < 4; ++gc) {
    f32x4 acc[4][4];
#pragma unroll
    for (int i = 0; i < 4; ++i)
#pragma unroll
      for (int j = 0; j < 4; ++j) acc[i][j] = (f32x4)(0.0f);

    // A-steps ks=0..6 prefetch next A-step; ks=7 prefetches R slice 0 and
    // writes proj slice 0 into buf0 (buf0 A/G regions dead after ks=6 barrier).
    for (int ks = 0; ks < 7; ++ks) {
      stageA(gc, ks + 1, (ks + 1) & 1);
      computeA(acc, ks & 1);
      __syncthreads();
    }
    stageR(gc, 0, 0);
    computeA(acc, 1);
    writeProj(acc, 0, 0);
    __syncthreads();

    // phase B: slice sl reads buf sl&1; slice sl+1 produced into buf^1 during
    // sl's compute. At sl==3, prefetch next gc's first A-step into buf0.
#pragma unroll
    for (int sl = 0; sl < 4; ++sl) {
      if (sl < 3) stageR(gc, sl + 1, (sl + 1) & 1);
      else if (gc < 3) stageA(gc + 1, 0, 0);
      computeB(sl & 1);
      if (sl < 3) writeProj(acc, sl + 1, (sl + 1) & 1);
      __syncthreads();
    }
  }

  // ---------- epilogue: fp16 stores to this block's own k-slice ----------
  const float vk = (brx ? v2 : v1)[k];
  unsigned short* dst = scoreH + (((size_t)brx * bc + b) * KC + k) * (SS * SS);
#pragma unroll
  for (int i = 0; i < 4; ++i)
#pragma unroll
    for (int j = 0; j < 4; ++j) {
      const int row0 = wm * 64 + i * 16 + q * 4;
      const int col = wn * 64 + j * 16 + c;
#pragma unroll
      for (int r = 0; r < 4; ++r)
        dst[(size_t)(row0 + r) * SS + col] = f2fp16(vk * tanh_fast(raw[i][j][r]));
    }
}

// ---- k-sum + softmax over t -> attn weights fp16 --------------------------
// grid (groups = bc*2, 8 rt); block = 16 s-rows x 128 t. scoreH is fp16.
__global__ __launch_bounds__(256) void softmax_attn(
    const unsigned short* __restrict__ scoreH, unsigned short* __restrict__ attnW) {
  const int x = blockIdx.x, rt = blockIdx.y;
  const int tid = threadIdx.x, tx = tid & 15, ty = tid >> 4;
  const size_t rowoff = (size_t)(rt * 16 + ty) * SS + tx * 8;
  const unsigned short* src = scoreH + (size_t)x * KC * (SS * SS) + rowoff;
  float sc[8];
#pragma unroll
  for (int j = 0; j < 8; ++j) sc[j] = 0.0f;
#pragma unroll
  for (int k = 0; k < KC; ++k) {
    f16x8 a = *(const f16x8*)&src[(size_t)k * (SS * SS)];
#pragma unroll
    for (int j = 0; j < 8; ++j) sc[j] += (float)a[j];
  }
  float mx = sc[0];
#pragma unroll
  for (int j = 1; j < 8; ++j) mx = fmaxf(mx, sc[j]);
#pragma unroll
  for (int off = 1; off < 16; off <<= 1) mx = fmaxf(mx, __shfl_xor(mx, off, 16));
  float p[8], ssum = 0.0f;
#pragma unroll
  for (int j = 0; j < 8; ++j) { p[j] = __expf(sc[j] - mx); ssum += p[j]; }
#pragma unroll
  for (int off = 1; off < 16; off <<= 1) ssum += __shfl_xor(ssum, off, 16);
  float inv = 1.0f / ssum;
  ushort4 h0, h1;
  h0.x = f2fp16(p[0] * inv); h0.y = f2fp16(p[1] * inv);
  h0.z = f2fp16(p[2] * inv); h0.w = f2fp16(p[3] * inv);
  h1.x = f2fp16(p[4] * inv); h1.y = f2fp16(p[5] * inv);
  h1.z = f2fp16(p[6] * inv); h1.w = f2fp16(p[7] * inv);
  size_t abase = (size_t)x * (SS * SS) + rowoff;
  *(ushort4*)&attnW[abase] = h0;
  *(ushort4*)&attnW[abase + 4] = h1;
}

// ---- PV + residual (fp16 MFMA): out = base + attn[64x128] @ V[128x128] ----
__global__ __launch_bounds__(256) void pv_res2(
    const unsigned short* __restrict__ attnW,
    const unsigned short* __restrict__ PTf, const unsigned short* __restrict__ ATf,
    const float* __restrict__ Abase, const float* __restrict__ Pbase,
    float* __restrict__ out1, float* __restrict__ out2, int bc) {
  __shared__ char smem[12288];  // A [64][32] 4 KB | B [128][32] 8 KB
  unsigned short* sm = (unsigned short*)smem;
  const int x = blockIdx.x;
  const int brx = (x >= bc) ? 1 : 0;
  const int b = x - (brx ? bc : 0);
  const int hc = blockIdx.y & 3, sh = blockIdx.y >> 2;
  const int tid = threadIdx.x, w = tid >> 6, L = tid & 63;
  const int wm = w >> 1, wn = w & 1;

  const unsigned short* Aw = attnW + (size_t)x * (SS * SS) + (size_t)(sh * 64) * SS;
  const unsigned short* Vh = (brx ? ATf : PTf) + (size_t)b * HH * SS + (size_t)(hc * 128) * SS;
  const float* base = (brx ? Pbase : Abase) + (size_t)b * SS * HH;
  float* outp = (brx ? out2 : out1) + (size_t)b * SS * HH;

  f32x4 acc[2][4];
#pragma unroll
  for (int i = 0; i < 2; ++i)
#pragma unroll
    for (int j = 0; j < 4; ++j) acc[i][j] = (f32x4)(0.0f);

  const int arow = w * 16 + (L >> 2);
  const int brow = w * 32 + (L >> 2);
  const int scol = (L & 3) * 8;
  const int afr = (wm * 32 + (L & 15)) * 32 + (L >> 4) * 8;
  const int bfr = 2048 + (wn * 64 + (L & 15)) * 32 + (L >> 4) * 8;

  for (int kt = 0; kt < 4; ++kt) {
    const int k0 = kt * 32;
    async16(Aw + (size_t)arow * SS + k0 + scol, smem + w * 1024);
    async16(Vh + (size_t)brow * SS + k0 + scol, smem + 4096 + w * 2048);
    async16(Vh + (size_t)(brow + 16) * SS + k0 + scol, smem + 4096 + w * 2048 + 1024);
    __syncthreads();
    f16x8 af[2], bf[4];
#pragma unroll
    for (int i = 0; i < 2; ++i) af[i] = *(const f16x8*)&sm[afr + i * 512];
#pragma unroll
    for (int j = 0; j < 4; ++j) bf[j] = *(const f16x8*)&sm[bfr + j * 512];
#pragma unroll
    for (int i = 0; i < 2; ++i)
#pragma unroll
      for (int j = 0; j < 4; ++j)
        acc[i][j] = __builtin_amdgcn_mfma_f32_16x16x32_f16(af[i], bf[j], acc[i][j], 0, 0, 0);
    __syncthreads();
  }

  const int q = L >> 4, c = L & 15;
#pragma unroll
  for (int i = 0; i < 2; ++i)
#pragma unroll
    for (int j = 0; j < 4; ++j) {
      const int srow = sh * 64 + wm * 32 + i * 16 + q * 4;
      const int hcol = hc * 128 + wn * 64 + j * 16 + c;
#pragma unroll
      for (int r = 0; r < 4; ++r) {
        size_t o = (size_t)(srow + r) * HH + hcol;
        outp[o] = base[o] + acc[i][j][r];
      }
    }
}

extern "C" void kernel_launch(void* const* d_in, const int* in_sizes, int n_in,
                              void* d_out, int out_size, void* d_ws, size_t ws_size,
                              hipStream_t stream) {
  const float* A  = (const float*)d_in[0];
  const float* P  = (const float*)d_in[1];
  const float* G1 = (const float*)d_in[2];
  const float* G2 = (const float*)d_in[3];
  const float* v1 = (const float*)d_in[4];
  const float* v2 = (const float*)d_in[5];
  float* out1 = (float*)d_out;
  float* out2 = out1 + (size_t)BB * SS * HH;

  const size_t NA = (size_t)BB * SS * HH;  // 2M
  const size_t NG = (size_t)HH * KC * HH;  // 2M
  unsigned short* Af16 = (unsigned short*)d_ws;
  unsigned short* Pf16 = Af16 + NA;
  unsigned short* G1f = Pf16 + NA;
  unsigned short* G2f = G1f + NG;
  unsigned short* ATf = G2f + NG;
  unsigned short* PTf = ATf + NA;

  const size_t fixedBytes = (4 * NA + 2 * NG) * sizeof(unsigned short);  // 24 MB
  // per batch: scoreH 2*KC*16K fp16 (512 KB) + attnW 2*16K fp16 (64 KB)
  const size_t perB = 2 * (size_t)SS * SS *
                      (KC * sizeof(unsigned short) + sizeof(unsigned short));
  size_t rem = ws_size > fixedBytes ? ws_size - fixedBytes : 0;
  int Bc = (int)(rem / perB);
  if (Bc < 1) Bc = 1;
  if (Bc > BB) Bc = BB;
  unsigned short* scoreH = (unsigned short*)((char*)d_ws + fixedBytes);
  unsigned short* attnW = scoreH + 2 * (size_t)Bc * KC * SS * SS;

  convert_all<<<dim3(8192), 256, 0, stream>>>(
      A, P, Af16, Pf16, ATf, PTf, G1, G2, G1f, G2f);

  for (int b0 = 0; b0 < BB; b0 += Bc) {
    int bc = (Bc < BB - b0) ? Bc : (BB - b0);
    size_t off = (size_t)b0 * SS * HH;  // element offset (both layouts)
    fused_score<<<dim3(KC, bc, 2), 256, 0, stream>>>(
        Af16 + off, Pf16 + off, G1f, G2f, v1, v2, scoreH, bc);
    softmax_attn<<<dim3(bc * 2, 8), 256, 0, stream>>>(scoreH, attnW);
    pv_res2<<<dim3(bc * 2, 8), 256, 0, stream>>>(
        attnW, PTf + off, ATf + off, A + off, P + off,
        out1 + off, out2 + off, bc);
  }
}